// Round 3
// baseline (852.595 us; speedup 1.0000x reference)
//
#include <hip/hip_runtime.h>
#include <math.h>

#define NN 25000
#define NE 400000
#define HD 64
#define EMBD 8
#define NG 16
#define NC 10

// ---------------------------------------------------------------------------
// Sort phase (once per launch; edge structure is layer-invariant).
// Build BOTH src-sorted order (gather locality) and dst-CSR (atomic-free
// scatter-reduce): perm[] maps src-sorted position -> dst-sorted position.
// ---------------------------------------------------------------------------
__global__ __launch_bounds__(256) void hist_k(const int* __restrict__ src,
        const int* __restrict__ dst, int* cnt_s, int* cnt_d) {
    int e = blockIdx.x * 256 + threadIdx.x;
    if (e < NE) {
        atomicAdd(&cnt_s[src[e]], 1);
        atomicAdd(&cnt_d[dst[e]], 1);
    }
}

// single block: exclusive scan of cnt_s -> cur_s, and cnt_d -> dstoff + cur_d
__global__ __launch_bounds__(1024) void scan2_k(const int* __restrict__ cnt_s,
        int* cur_s, const int* __restrict__ cnt_d, int* dstoff, int* cur_d) {
    __shared__ int sh[1024];
    __shared__ int carry;
    int tx = threadIdx.x;
    for (int pass = 0; pass < 2; pass++) {
        const int* in = pass ? cnt_d : cnt_s;
        if (tx == 0) carry = 0;
        __syncthreads();
        for (int c0 = 0; c0 < NN; c0 += 1024) {
            int i = c0 + tx;
            int v = (i < NN) ? in[i] : 0;
            sh[tx] = v;
            __syncthreads();
            for (int off = 1; off < 1024; off <<= 1) {
                int t = (tx >= off) ? sh[tx - off] : 0;
                __syncthreads();
                sh[tx] += t;
                __syncthreads();
            }
            int excl = carry + sh[tx] - v;
            if (i < NN) {
                if (pass == 0) {
                    cur_s[i] = excl;
                } else {
                    dstoff[i] = excl;
                    cur_d[i] = excl;
                }
            }
            int total = sh[1023];
            __syncthreads();
            if (tx == 0) carry += total;
            __syncthreads();
        }
    }
    if (tx == 0) dstoff[NN] = NE;
}

// scatter: place edge at src-sorted slot, record its dst-sorted slot (perm),
// compute normalized direction at the src-sorted slot.
__global__ __launch_bounds__(256) void scatter_k(const int* __restrict__ src,
        const int* __restrict__ dst, const float* __restrict__ c,
        int* cur_s, int* cur_d, int* __restrict__ src_s, int* __restrict__ dst_s,
        int* __restrict__ perm, float* __restrict__ dnorm_s) {
    int e = blockIdx.x * 256 + threadIdx.x;
    if (e >= NE) return;
    int s = src[e], t = dst[e];
    int ps = atomicAdd(&cur_s[s], 1);
    int pd = atomicAdd(&cur_d[t], 1);
    src_s[ps] = s;
    dst_s[ps] = t;
    perm[ps] = pd;
    float d[8];
#pragma unroll
    for (int i = 0; i < 8; i++) d[i] = c[s * 8 + i] - c[t * 8 + i];
    float nn = 0.f;
#pragma unroll
    for (int i = 0; i < 8; i++) nn += d[i] * d[i];
    float inv = 1.f / fmaxf(sqrtf(nn), 1e-12f);
    float4 lo = make_float4(d[0] * inv, d[1] * inv, d[2] * inv, d[3] * inv);
    float4 hi = make_float4(d[4] * inv, d[5] * inv, d[6] * inv, d[7] * inv);
    *(float4*)(dnorm_s + (size_t)ps * 8)     = lo;
    *(float4*)(dnorm_s + (size_t)ps * 8 + 4) = hi;
}

// ---------------------------------------------------------------------------
// K1: Z[n, i*64+k] = sum_j h[n,j] * W[i,j,k]
// ---------------------------------------------------------------------------
__global__ __launch_bounds__(256) void node_gemm_k(const float* __restrict__ h,
        const float* __restrict__ W, float* __restrict__ Z) {
    __shared__ float hsT[64][68];
    __shared__ float Ws[64][64];
    int n0 = blockIdx.x * 64;
    int i  = blockIdx.y;
    int tx = threadIdx.x;

    for (int t = tx; t < 4096; t += 256)
        Ws[t >> 6][t & 63] = W[i * 4096 + t];
    for (int t = tx; t < 4096; t += 256) {
        int r = t >> 6, j = t & 63;
        int n = n0 + r;
        hsT[j][r] = (n < NN) ? h[(size_t)n * 64 + j] : 0.f;
    }
    __syncthreads();

    int col0 = (tx & 15) * 4;
    int row0 = (tx >> 4) * 4;
    float acc[4][4] = {{0.f}};
#pragma unroll 8
    for (int j = 0; j < 64; j++) {
        float4 a = *(const float4*)&hsT[j][row0];
        float4 b = *(const float4*)&Ws[j][col0];
        float a4[4] = {a.x, a.y, a.z, a.w};
        float b4[4] = {b.x, b.y, b.z, b.w};
#pragma unroll
        for (int r = 0; r < 4; r++)
#pragma unroll
            for (int cc = 0; cc < 4; cc++)
                acc[r][cc] = fmaf(a4[r], b4[cc], acc[r][cc]);
    }
#pragma unroll
    for (int r = 0; r < 4; r++) {
        int n = n0 + row0 + r;
        if (n < NN) {
            float4 v = make_float4(acc[r][0], acc[r][1], acc[r][2], acc[r][3]);
            *(float4*)(Z + (size_t)n * 512 + i * 64 + col0) = v;
        }
    }
}

// ---------------------------------------------------------------------------
// K2a (two-phase mode): src-sorted gather, register-cached Z row; plain
// scattered store of msg to its dst-sorted slot. No atomics.
// ---------------------------------------------------------------------------
#define NWAVES_A 8192
__global__ __launch_bounds__(256) void edge_msg_store_k(const float* __restrict__ dnorm,
        const int* __restrict__ src_s, const int* __restrict__ perm,
        const float* __restrict__ Z, float* __restrict__ msgbuf) {
    int gid  = blockIdx.x * 256 + threadIdx.x;
    int wave = gid >> 6;
    int lane = threadIdx.x & 63;
    const int cpw = (NE + NWAVES_A - 1) / NWAVES_A;
    int e0 = wave * cpw;
    int e1 = min(e0 + cpw, NE);
    int sprev = -1;
    float z0=0,z1=0,z2=0,z3=0,z4=0,z5=0,z6=0,z7=0;
    for (int e = e0; e < e1; e++) {
        int s = src_s[e];
        int pd = perm[e];
        if (s != sprev) {
            const float* zp = Z + (size_t)s * 512 + lane;
            z0 = zp[0*64]; z1 = zp[1*64]; z2 = zp[2*64]; z3 = zp[3*64];
            z4 = zp[4*64]; z5 = zp[5*64]; z6 = zp[6*64]; z7 = zp[7*64];
            sprev = s;
        }
        const float* dp = dnorm + (size_t)e * 8;
        float4 dA = *(const float4*)(dp);
        float4 dB = *(const float4*)(dp + 4);
        float m = 0.f;
        m = fmaf(dA.x, z0, m); m = fmaf(dA.y, z1, m);
        m = fmaf(dA.z, z2, m); m = fmaf(dA.w, z3, m);
        m = fmaf(dB.x, z4, m); m = fmaf(dB.y, z5, m);
        m = fmaf(dB.z, z6, m); m = fmaf(dB.w, z7, m);
        msgbuf[(size_t)pd * 64 + lane] = m;
    }
}

// K2b: dst-CSR segment sum of msgbuf -> agg; fused relu BN-stats reduction.
__global__ __launch_bounds__(256) void seg_sum_k(const float* __restrict__ msgbuf,
        const int* __restrict__ dstoff, float* __restrict__ agg,
        float* sums, float* sumsq) {
    __shared__ float ls[256], ls2[256];
    int gid  = blockIdx.x * 256 + threadIdx.x;
    int wave = gid >> 6;
    int lane = threadIdx.x & 63;
    int nwaves = (gridDim.x * 256) >> 6;
    float s = 0.f, s2 = 0.f;
    for (int n = wave; n < NN; n += nwaves) {
        int p0 = dstoff[n], p1 = dstoff[n + 1];
        float acc = 0.f;
        for (int p = p0; p < p1; p++)
            acc += msgbuf[(size_t)p * 64 + lane];
        agg[(size_t)n * 64 + lane] = acc;
        float x = fmaxf(acc, 0.f);
        s += x;
        s2 += x * x;
    }
    ls[threadIdx.x] = s; ls2[threadIdx.x] = s2;
    __syncthreads();
    if (threadIdx.x < 64) {
        int tx = threadIdx.x;
        s  = ls[tx] + ls[tx + 64] + ls[tx + 128] + ls[tx + 192];
        s2 = ls2[tx] + ls2[tx + 64] + ls2[tx + 128] + ls2[tx + 192];
        atomicAdd(&sums[tx], s);
        atomicAdd(&sumsq[tx], s2);
    }
}

// ---------------------------------------------------------------------------
// K2-fallback (small ws): R2-style atomic accumulation
// ---------------------------------------------------------------------------
#define NWAVES_F 4096
__global__ __launch_bounds__(256) void edge_msg_atomic_k(const float* __restrict__ dnorm,
        const int* __restrict__ src_s, const int* __restrict__ dst_s,
        const float* __restrict__ Z, float* agg) {
    int gid  = blockIdx.x * 256 + threadIdx.x;
    int wave = gid >> 6;
    int lane = threadIdx.x & 63;
    const int cpw = (NE + NWAVES_F - 1) / NWAVES_F;
    int e0 = wave * cpw;
    int e1 = min(e0 + cpw, NE);
    int sprev = -1;
    float z0=0,z1=0,z2=0,z3=0,z4=0,z5=0,z6=0,z7=0;
    for (int e = e0; e < e1; e++) {
        int s = src_s[e];
        int t = dst_s[e];
        if (s != sprev) {
            const float* zp = Z + (size_t)s * 512 + lane;
            z0 = zp[0*64]; z1 = zp[1*64]; z2 = zp[2*64]; z3 = zp[3*64];
            z4 = zp[4*64]; z5 = zp[5*64]; z6 = zp[6*64]; z7 = zp[7*64];
            sprev = s;
        }
        const float* dp = dnorm + (size_t)e * 8;
        float4 dA = *(const float4*)(dp);
        float4 dB = *(const float4*)(dp + 4);
        float m = 0.f;
        m = fmaf(dA.x, z0, m); m = fmaf(dA.y, z1, m);
        m = fmaf(dA.z, z2, m); m = fmaf(dA.w, z3, m);
        m = fmaf(dB.x, z4, m); m = fmaf(dB.y, z5, m);
        m = fmaf(dB.z, z6, m); m = fmaf(dB.w, z7, m);
        atomicAdd(agg + (size_t)t * 64 + lane, m);
    }
}

__global__ __launch_bounds__(256) void bn_stats_k(const float* __restrict__ agg,
        float* sums, float* sumsq) {
    __shared__ float ls[256], ls2[256];
    int tx = threadIdx.x;
    int idx0 = blockIdx.x * 256 + tx;
    int stride = gridDim.x * 256;
    float s = 0.f, s2 = 0.f;
    for (int idx = idx0; idx < NN * 64; idx += stride) {
        float x = fmaxf(agg[idx], 0.f);
        s += x;
        s2 += x * x;
    }
    ls[tx] = s; ls2[tx] = s2;
    __syncthreads();
    if (tx < 64) {
        s  = ls[tx] + ls[tx + 64] + ls[tx + 128] + ls[tx + 192];
        s2 = ls2[tx] + ls2[tx + 64] + ls2[tx + 128] + ls2[tx + 192];
        atomicAdd(&sums[tx], s);
        atomicAdd(&sumsq[tx], s2);
    }
}

// ---------------------------------------------------------------------------
// K4: BN apply + shortcut + graph pooling
// ---------------------------------------------------------------------------
__global__ __launch_bounds__(256) void bn_apply_k(const float* agg,
        const float* __restrict__ h_old, const float* __restrict__ sums,
        const float* __restrict__ sumsq, const float* __restrict__ gamma,
        const float* __restrict__ beta, const int* __restrict__ gids,
        float* h_new, float* pooled, int shortcut) {
    __shared__ float pl[NG * 64];
    int tx = threadIdx.x;
    for (int t = tx; t < NG * 64; t += 256) pl[t] = 0.f;
    __syncthreads();

    int k = tx & 63;
    float mean = sums[k] * (1.f / NN);
    float var  = sumsq[k] * (1.f / NN) - mean * mean;
    float rstd = rsqrtf(var + 1e-5f);
    float g = gamma[k], b = beta[k];

    int idx0 = blockIdx.x * 256 + tx;
    int stride = gridDim.x * 256;
    for (int idx = idx0; idx < NN * 64; idx += stride) {
        int n = idx >> 6;
        float x = fmaxf(agg[idx], 0.f);
        float y = g * (x - mean) * rstd + b;
        if (shortcut) y += h_old[idx];
        h_new[idx] = y;
        atomicAdd(&pl[gids[n] * 64 + k], y);
    }
    __syncthreads();
    for (int t = tx; t < NG * 64; t += 256) {
        float v = pl[t];
        if (v != 0.f) atomicAdd(&pooled[t], v);
    }
}

// ---------------------------------------------------------------------------
// K5: classifier (single block)
// ---------------------------------------------------------------------------
__global__ __launch_bounds__(512) void classifier_k(const float* __restrict__ pooled,
        const float* __restrict__ cW1, const float* __restrict__ cb1,
        const float* __restrict__ cg1, const float* __restrict__ cbt1,
        const float* __restrict__ cW2, const float* __restrict__ cb2,
        float* logits) {
    __shared__ float P[NG * 64];
    __shared__ float H1[NG * 32];
    __shared__ float cmu[32], crs[32];
    int tx = threadIdx.x;
    for (int t = tx; t < NG * 64; t += 512) P[t] = pooled[t];
    __syncthreads();

    int gidx = tx >> 5;
    int c    = tx & 31;
    float acc = cb1[c];
#pragma unroll 16
    for (int j = 0; j < 64; j++) acc = fmaf(P[gidx * 64 + j], cW1[j * 32 + c], acc);
    H1[gidx * 32 + c] = acc;
    __syncthreads();

    if (tx < 32) {
        float mu = 0.f;
#pragma unroll
        for (int g2 = 0; g2 < NG; g2++) mu += H1[g2 * 32 + tx];
        mu *= (1.f / NG);
        float v = 0.f;
#pragma unroll
        for (int g2 = 0; g2 < NG; g2++) {
            float d = H1[g2 * 32 + tx] - mu;
            v += d * d;
        }
        v *= (1.f / NG);
        cmu[tx] = mu;
        crs[tx] = rsqrtf(v + 1e-5f);
    }
    __syncthreads();

    float h1 = fmaxf(cg1[c] * (H1[gidx * 32 + c] - cmu[c]) * crs[c] + cbt1[c], 0.f);
    __syncthreads();
    H1[gidx * 32 + c] = h1;
    __syncthreads();

    if (tx < NG * NC) {
        int gg = tx / NC, cls = tx % NC;
        float a2 = cb2[cls];
#pragma unroll
        for (int j = 0; j < 32; j++) a2 = fmaf(H1[gg * 32 + j], cW2[j * NC + cls], a2);
        logits[tx] += a2;
    }
}

// ---------------------------------------------------------------------------
extern "C" void kernel_launch(void* const* d_in, const int* in_sizes, int n_in,
                              void* d_out, int out_size, void* d_ws, size_t ws_size,
                              hipStream_t stream) {
    const float* feature = (const float*)d_in[0];
    const float* cemb    = (const float*)d_in[1];
    const int*   src     = (const int*)d_in[2];
    const int*   dst     = (const int*)d_in[3];
    const int*   gids    = (const int*)d_in[4];
    const float* W[3]    = {(const float*)d_in[5], (const float*)d_in[6], (const float*)d_in[7]};
    const float* gam[3]  = {(const float*)d_in[8], (const float*)d_in[10], (const float*)d_in[12]};
    const float* bet[3]  = {(const float*)d_in[9], (const float*)d_in[11], (const float*)d_in[13]};
    const float* cW1  = (const float*)d_in[14];
    const float* cb1  = (const float*)d_in[15];
    const float* cg1  = (const float*)d_in[16];
    const float* cbt1 = (const float*)d_in[17];
    const float* cW2  = (const float*)d_in[18];
    const float* cb2  = (const float*)d_in[19];
    float* out = (float*)d_out;

    // workspace layout (4-byte units)
    float* ws      = (float*)d_ws;
    float* dnorm_s = ws;                          // NE*8     = 3,200,000
    float* Z       = dnorm_s + (size_t)NE * 8;    // NN*512   = 12,800,000
    float* bufX    = Z + (size_t)NN * 512;        // NN*64
    float* bufY    = bufX + (size_t)NN * 64;      // NN*64
    float* sums    = bufY + (size_t)NN * 64;      // 64
    float* sumsq   = sums + 64;                   // 64
    float* pooled  = sumsq + 64;                  // 1024 (stats block = 2048 total)
    int*   cnt_s   = (int*)(sums + 2048);         // NN
    int*   cnt_d   = cnt_s + NN;                  // NN
    int*   cur_s   = cnt_d + NN;                  // NN
    int*   cur_d   = cur_s + NN;                  // NN
    int*   dstoff  = cur_d + NN;                  // NN+1 (pad to NN+8)
    int*   src_s   = dstoff + NN + 8;             // NE
    int*   dst_s   = src_s + NE;                  // NE
    int*   perm    = dst_s + NE;                  // NE
    float* msgbuf  = (float*)(perm + NE);         // NE*64 = 25,600,000 (optional)

    size_t need_two_phase = ((size_t)(msgbuf - ws) + (size_t)NE * 64) * 4;
    int two_phase = ws_size >= need_two_phase;

    hipMemsetAsync(d_out, 0, (size_t)NG * NC * sizeof(float), stream);
    hipMemsetAsync(cnt_s, 0, 2 * NN * sizeof(int), stream);

    // build orderings once (layer-invariant)
    hist_k<<<(NE + 255) / 256, 256, 0, stream>>>(src, dst, cnt_s, cnt_d);
    scan2_k<<<1, 1024, 0, stream>>>(cnt_s, cur_s, cnt_d, dstoff, cur_d);
    scatter_k<<<(NE + 255) / 256, 256, 0, stream>>>(src, dst, cemb, cur_s, cur_d,
                                                    src_s, dst_s, perm, dnorm_s);

    const float* h_old = feature;
    float* bufs[2] = {bufX, bufY};
    for (int l = 0; l < 3; l++) {
        float* agg = bufs[l & 1];
        hipMemsetAsync(sums, 0, 2048 * sizeof(float), stream);

        node_gemm_k<<<dim3((NN + 63) / 64, 8), 256, 0, stream>>>(h_old, W[l], Z);
        if (two_phase) {
            edge_msg_store_k<<<NWAVES_A / 4, 256, 0, stream>>>(dnorm_s, src_s, perm, Z, msgbuf);
            seg_sum_k<<<512, 256, 0, stream>>>(msgbuf, dstoff, agg, sums, sumsq);
        } else {
            hipMemsetAsync(agg, 0, (size_t)NN * 64 * sizeof(float), stream);
            edge_msg_atomic_k<<<NWAVES_F / 4, 256, 0, stream>>>(dnorm_s, src_s, dst_s, Z, agg);
            bn_stats_k<<<256, 256, 0, stream>>>(agg, sums, sumsq);
        }
        bn_apply_k<<<256, 256, 0, stream>>>(agg, h_old, sums, sumsq, gam[l], bet[l],
                                            gids, agg, pooled, l > 0);
        classifier_k<<<1, 512, 0, stream>>>(pooled, cW1, cb1, cg1, cbt1, cW2, cb2, out);
        h_old = agg;
    }
}

// Round 4
// 687.072 us; speedup vs baseline: 1.2409x; 1.2409x over previous
//
#include <hip/hip_runtime.h>
#include <math.h>

#define NN 25000
#define NE 400000
#define HD 64
#define EMBD 8
#define NG 16
#define NC 10
#define SCAN_NB 98   // ceil(NN/256)

// ---------------------------------------------------------------------------
// Sort phase: dst-CSR only (edge structure is layer-invariant).
// ---------------------------------------------------------------------------
__global__ __launch_bounds__(256) void hist_k(const int* __restrict__ dst, int* cnt) {
    int e = blockIdx.x * 256 + threadIdx.x;
    if (e < NE) atomicAdd(&cnt[dst[e]], 1);
}

// block partial sums
__global__ __launch_bounds__(256) void scan_part_k(const int* __restrict__ cnt, int* bsum) {
    __shared__ int sh[256];
    int tx = threadIdx.x;
    int i = blockIdx.x * 256 + tx;
    sh[tx] = (i < NN) ? cnt[i] : 0;
    __syncthreads();
    for (int off = 128; off > 0; off >>= 1) {
        if (tx < off) sh[tx] += sh[tx + off];
        __syncthreads();
    }
    if (tx == 0) bsum[blockIdx.x] = sh[0];
}

// single small block: exclusive scan of 98 block sums
__global__ __launch_bounds__(128) void scan_mid_k(const int* __restrict__ bsum,
        int* boff, int* dstoff) {
    __shared__ int sh[128];
    int tx = threadIdx.x;
    int v = (tx < SCAN_NB) ? bsum[tx] : 0;
    sh[tx] = v;
    __syncthreads();
    for (int off = 1; off < 128; off <<= 1) {
        int t = (tx >= off) ? sh[tx - off] : 0;
        __syncthreads();
        sh[tx] += t;
        __syncthreads();
    }
    if (tx < SCAN_NB) boff[tx] = sh[tx] - v;   // exclusive
    if (tx == 0) dstoff[NN] = NE;
}

// intra-block scan + block offset -> dstoff (pristine) and cur (bumpable copy)
__global__ __launch_bounds__(256) void scan_final_k(const int* __restrict__ cnt,
        const int* __restrict__ boff, int* dstoff, int* cur) {
    __shared__ int sh[256];
    int tx = threadIdx.x;
    int i = blockIdx.x * 256 + tx;
    int v = (i < NN) ? cnt[i] : 0;
    sh[tx] = v;
    __syncthreads();
    for (int off = 1; off < 256; off <<= 1) {
        int t = (tx >= off) ? sh[tx - off] : 0;
        __syncthreads();
        sh[tx] += t;
        __syncthreads();
    }
    int excl = boff[blockIdx.x] + sh[tx] - v;
    if (i < NN) { dstoff[i] = excl; cur[i] = excl; }
}

// place each edge's src at its dst-sorted slot
__global__ __launch_bounds__(256) void scatter_k(const int* __restrict__ src,
        const int* __restrict__ dst, int* cur, int* __restrict__ src_d) {
    int e = blockIdx.x * 256 + threadIdx.x;
    if (e >= NE) return;
    int pd = atomicAdd(&cur[dst[e]], 1);
    src_d[pd] = src[e];
}

// ---------------------------------------------------------------------------
// K1: E[t, i*64+j] = sum_{e->t} dnorm[e,i] * h[src_e, j]
// Wave = 64 h-channels (j = lane), 8 regs = i. Dst-CSR walk, node-granular
// wave partition (binary search) -> plain sequential stores, zero atomics.
// dnorm computed on the fly from cemb (no dnorm array at all).
// ---------------------------------------------------------------------------
#define NWE 8192
__global__ __launch_bounds__(256) void edge_E_k(const int* __restrict__ src_d,
        const int* __restrict__ dstoff, const float* __restrict__ cemb,
        const float* __restrict__ h, float* __restrict__ E) {
    int gid  = blockIdx.x * 256 + threadIdx.x;
    int w    = gid >> 6;
    int lane = threadIdx.x & 63;
    long long t0 = (long long)w * NE / NWE;
    long long t1 = (long long)(w + 1) * NE / NWE;
    // first n with dstoff[n] >= t0
    int lo = 0, hi = NN;
    while (lo < hi) { int mid = (lo + hi) >> 1; if (dstoff[mid] < t0) lo = mid + 1; else hi = mid; }
    int nlo = lo;
    lo = 0; hi = NN;
    while (lo < hi) { int mid = (lo + hi) >> 1; if (dstoff[mid] < t1) lo = mid + 1; else hi = mid; }
    int nhi = (w == NWE - 1) ? NN : lo;

    for (int n = nlo; n < nhi; n++) {
        float e0=0,e1=0,e2=0,e3=0,e4=0,e5=0,e6=0,e7=0;
        int p0 = dstoff[n], p1 = dstoff[n + 1];
        float4 na = *(const float4*)(cemb + (size_t)n * 8);
        float4 nb = *(const float4*)(cemb + (size_t)n * 8 + 4);
        for (int p = p0; p < p1; p++) {
            int s = src_d[p];
            float4 sa = *(const float4*)(cemb + (size_t)s * 8);
            float4 sb = *(const float4*)(cemb + (size_t)s * 8 + 4);
            float d0 = sa.x - na.x, d1 = sa.y - na.y, d2 = sa.z - na.z, d3 = sa.w - na.w;
            float d4 = sb.x - nb.x, d5 = sb.y - nb.y, d6 = sb.z - nb.z, d7 = sb.w - nb.w;
            float nn2 = d0*d0 + d1*d1 + d2*d2 + d3*d3 + d4*d4 + d5*d5 + d6*d6 + d7*d7;
            float inv = 1.f / fmaxf(sqrtf(nn2), 1e-12f);
            float hv = h[(size_t)s * 64 + lane];
            float hi2 = hv * inv;
            e0 = fmaf(d0, hi2, e0); e1 = fmaf(d1, hi2, e1);
            e2 = fmaf(d2, hi2, e2); e3 = fmaf(d3, hi2, e3);
            e4 = fmaf(d4, hi2, e4); e5 = fmaf(d5, hi2, e5);
            e6 = fmaf(d6, hi2, e6); e7 = fmaf(d7, hi2, e7);
        }
        float* ep = E + (size_t)n * 512 + lane;
        ep[0*64] = e0; ep[1*64] = e1; ep[2*64] = e2; ep[3*64] = e3;
        ep[4*64] = e4; ep[5*64] = e5; ep[6*64] = e6; ep[7*64] = e7;
    }
}

// ---------------------------------------------------------------------------
// K2: agg[n,k] = sum_q E[n,q] * W[q,k]   (W input is [8,64,64] == [512,64])
// 64x64 tile per block, K=512 in 8 chunks. Fused relu BN-stats epilogue.
// ---------------------------------------------------------------------------
__global__ __launch_bounds__(256) void finish_gemm_k(const float* __restrict__ E,
        const float* __restrict__ W, float* __restrict__ agg,
        float* sums, float* sumsq) {
    __shared__ float Et[64][68];   // [q_local][node_local]
    __shared__ float Wsh[64][64];  // [q_local][k]
    int n0 = blockIdx.x * 64;
    int tx = threadIdx.x;
    int col0 = (tx & 15) * 4;
    int row0 = (tx >> 4) * 4;
    float acc[4][4] = {{0.f}};

    for (int kc = 0; kc < 8; kc++) {
        __syncthreads();
        for (int t = tx; t < 4096; t += 256) {
            int r = t >> 6, q = t & 63;
            int n = n0 + r;
            Et[q][r] = (n < NN) ? E[(size_t)n * 512 + kc * 64 + q] : 0.f;
        }
        for (int t = tx; t < 4096; t += 256)
            Wsh[t >> 6][t & 63] = W[kc * 4096 + t];
        __syncthreads();
#pragma unroll 8
        for (int q = 0; q < 64; q++) {
            float4 a = *(const float4*)&Et[q][row0];
            float4 b = *(const float4*)&Wsh[q][col0];
            float a4[4] = {a.x, a.y, a.z, a.w};
            float b4[4] = {b.x, b.y, b.z, b.w};
#pragma unroll
            for (int r = 0; r < 4; r++)
#pragma unroll
                for (int c = 0; c < 4; c++)
                    acc[r][c] = fmaf(a4[r], b4[c], acc[r][c]);
        }
    }

    // store + per-thread relu stats
    float s1v[4] = {0.f}, s2v[4] = {0.f};
#pragma unroll
    for (int r = 0; r < 4; r++) {
        int n = n0 + row0 + r;
        if (n < NN) {
            *(float4*)(agg + (size_t)n * 64 + col0) =
                make_float4(acc[r][0], acc[r][1], acc[r][2], acc[r][3]);
#pragma unroll
            for (int c = 0; c < 4; c++) {
                float x = fmaxf(acc[r][c], 0.f);
                s1v[c] += x;
                s2v[c] += x * x;
            }
        }
    }
    // LDS reduction over the 16 row-groups (reuse Et storage)
    __syncthreads();
    float* r1 = (float*)Et;            // 16*64
    float* r2 = r1 + 1024;             // 16*64
    int grp = tx >> 4;
#pragma unroll
    for (int c = 0; c < 4; c++) {
        r1[grp * 64 + col0 + c] = s1v[c];
        r2[grp * 64 + col0 + c] = s2v[c];
    }
    __syncthreads();
    if (tx < 64) {
        float a = 0.f, b = 0.f;
#pragma unroll
        for (int g = 0; g < 16; g++) { a += r1[g * 64 + tx]; b += r2[g * 64 + tx]; }
        atomicAdd(&sums[tx], a);
        atomicAdd(&sumsq[tx], b);
    }
}

// ---------------------------------------------------------------------------
// K4: BN apply + shortcut + graph pooling
// ---------------------------------------------------------------------------
__global__ __launch_bounds__(256) void bn_apply_k(const float* agg,
        const float* __restrict__ h_old, const float* __restrict__ sums,
        const float* __restrict__ sumsq, const float* __restrict__ gamma,
        const float* __restrict__ beta, const int* __restrict__ gids,
        float* h_new, float* pooled, int shortcut) {
    __shared__ float pl[NG * 64];
    int tx = threadIdx.x;
    for (int t = tx; t < NG * 64; t += 256) pl[t] = 0.f;
    __syncthreads();

    int k = tx & 63;
    float mean = sums[k] * (1.f / NN);
    float var  = sumsq[k] * (1.f / NN) - mean * mean;
    float rstd = rsqrtf(var + 1e-5f);
    float g = gamma[k], b = beta[k];

    int idx0 = blockIdx.x * 256 + tx;
    int stride = gridDim.x * 256;
    for (int idx = idx0; idx < NN * 64; idx += stride) {
        int n = idx >> 6;
        float x = fmaxf(agg[idx], 0.f);
        float y = g * (x - mean) * rstd + b;
        if (shortcut) y += h_old[idx];
        h_new[idx] = y;
        atomicAdd(&pl[gids[n] * 64 + k], y);
    }
    __syncthreads();
    for (int t = tx; t < NG * 64; t += 256) {
        float v = pl[t];
        if (v != 0.f) atomicAdd(&pooled[t], v);
    }
}

// ---------------------------------------------------------------------------
// K5: classifier (single block)
// ---------------------------------------------------------------------------
__global__ __launch_bounds__(512) void classifier_k(const float* __restrict__ pooled,
        const float* __restrict__ cW1, const float* __restrict__ cb1,
        const float* __restrict__ cg1, const float* __restrict__ cbt1,
        const float* __restrict__ cW2, const float* __restrict__ cb2,
        float* logits) {
    __shared__ float P[NG * 64];
    __shared__ float H1[NG * 32];
    __shared__ float cmu[32], crs[32];
    int tx = threadIdx.x;
    for (int t = tx; t < NG * 64; t += 512) P[t] = pooled[t];
    __syncthreads();

    int gidx = tx >> 5;
    int c    = tx & 31;
    float acc = cb1[c];
#pragma unroll 16
    for (int j = 0; j < 64; j++) acc = fmaf(P[gidx * 64 + j], cW1[j * 32 + c], acc);
    H1[gidx * 32 + c] = acc;
    __syncthreads();

    if (tx < 32) {
        float mu = 0.f;
#pragma unroll
        for (int g2 = 0; g2 < NG; g2++) mu += H1[g2 * 32 + tx];
        mu *= (1.f / NG);
        float v = 0.f;
#pragma unroll
        for (int g2 = 0; g2 < NG; g2++) {
            float d = H1[g2 * 32 + tx] - mu;
            v += d * d;
        }
        v *= (1.f / NG);
        cmu[tx] = mu;
        crs[tx] = rsqrtf(v + 1e-5f);
    }
    __syncthreads();

    float h1 = fmaxf(cg1[c] * (H1[gidx * 32 + c] - cmu[c]) * crs[c] + cbt1[c], 0.f);
    __syncthreads();
    H1[gidx * 32 + c] = h1;
    __syncthreads();

    if (tx < NG * NC) {
        int gg = tx / NC, cls = tx % NC;
        float a2 = cb2[cls];
#pragma unroll
        for (int j = 0; j < 32; j++) a2 = fmaf(H1[gg * 32 + j], cW2[j * NC + cls], a2);
        logits[tx] += a2;
    }
}

// ---------------------------------------------------------------------------
extern "C" void kernel_launch(void* const* d_in, const int* in_sizes, int n_in,
                              void* d_out, int out_size, void* d_ws, size_t ws_size,
                              hipStream_t stream) {
    const float* feature = (const float*)d_in[0];
    const float* cemb    = (const float*)d_in[1];
    const int*   src     = (const int*)d_in[2];
    const int*   dst     = (const int*)d_in[3];
    const int*   gids    = (const int*)d_in[4];
    const float* W[3]    = {(const float*)d_in[5], (const float*)d_in[6], (const float*)d_in[7]};
    const float* gam[3]  = {(const float*)d_in[8], (const float*)d_in[10], (const float*)d_in[12]};
    const float* bet[3]  = {(const float*)d_in[9], (const float*)d_in[11], (const float*)d_in[13]};
    const float* cW1  = (const float*)d_in[14];
    const float* cb1  = (const float*)d_in[15];
    const float* cg1  = (const float*)d_in[16];
    const float* cbt1 = (const float*)d_in[17];
    const float* cW2  = (const float*)d_in[18];
    const float* cb2  = (const float*)d_in[19];
    float* out = (float*)d_out;

    // workspace layout (4-byte units)
    float* ws      = (float*)d_ws;
    float* E       = ws;                          // NN*512 = 12,800,000
    float* bufX    = E + (size_t)NN * 512;        // NN*64
    float* bufY    = bufX + (size_t)NN * 64;      // NN*64
    float* sums    = bufY + (size_t)NN * 64;      // 64
    float* sumsq   = sums + 64;                   // 64
    float* pooled  = sumsq + 64;                  // 1024 (block reserved: 2048)
    int*   cnt     = (int*)(sums + 2048);         // NN
    int*   cur     = cnt + NN;                    // NN
    int*   dstoff  = cur + NN;                    // NN+1 (pad +8)
    int*   bsum    = dstoff + NN + 8;             // 128
    int*   boff    = bsum + 128;                  // 128
    int*   src_d   = boff + 128;                  // NE

    hipMemsetAsync(d_out, 0, (size_t)NG * NC * sizeof(float), stream);
    hipMemsetAsync(cnt, 0, NN * sizeof(int), stream);

    // dst-CSR build (layer-invariant), fast multi-block scan
    hist_k<<<(NE + 255) / 256, 256, 0, stream>>>(dst, cnt);
    scan_part_k<<<SCAN_NB, 256, 0, stream>>>(cnt, bsum);
    scan_mid_k<<<1, 128, 0, stream>>>(bsum, boff, dstoff);
    scan_final_k<<<SCAN_NB, 256, 0, stream>>>(cnt, boff, dstoff, cur);
    scatter_k<<<(NE + 255) / 256, 256, 0, stream>>>(src, dst, cur, src_d);

    const float* h_old = feature;
    float* bufs[2] = {bufX, bufY};
    for (int l = 0; l < 3; l++) {
        float* agg = bufs[l & 1];
        hipMemsetAsync(sums, 0, 2048 * sizeof(float), stream);

        edge_E_k<<<NWE / 4, 256, 0, stream>>>(src_d, dstoff, cemb, h_old, E);
        finish_gemm_k<<<(NN + 63) / 64, 256, 0, stream>>>(E, W[l], agg, sums, sumsq);
        bn_apply_k<<<256, 256, 0, stream>>>(agg, h_old, sums, sumsq, gam[l], bet[l],
                                            gids, agg, pooled, l > 0);
        classifier_k<<<1, 512, 0, stream>>>(pooled, cW1, cb1, cg1, cbt1, cW2, cb2, out);
        h_old = agg;
    }
}

// Round 5
// 627.199 us; speedup vs baseline: 1.3594x; 1.0955x over previous
//
#include <hip/hip_runtime.h>
#include <math.h>

#define NN 25000
#define NE 400000
#define HD 64
#define EMBD 8
#define NG 16
#define NC 10
#define SCAN_NB 98   // ceil(NN/256)

// ---------------------------------------------------------------------------
// Sort phase: dst-CSR (edge structure is layer-invariant).
// ---------------------------------------------------------------------------
__global__ __launch_bounds__(256) void hist_k(const int* __restrict__ dst, int* cnt) {
    int e = blockIdx.x * 256 + threadIdx.x;
    if (e < NE) atomicAdd(&cnt[dst[e]], 1);
}

__global__ __launch_bounds__(256) void scan_part_k(const int* __restrict__ cnt, int* bsum) {
    __shared__ int sh[256];
    int tx = threadIdx.x;
    int i = blockIdx.x * 256 + tx;
    sh[tx] = (i < NN) ? cnt[i] : 0;
    __syncthreads();
    for (int off = 128; off > 0; off >>= 1) {
        if (tx < off) sh[tx] += sh[tx + off];
        __syncthreads();
    }
    if (tx == 0) bsum[blockIdx.x] = sh[0];
}

__global__ __launch_bounds__(128) void scan_mid_k(const int* __restrict__ bsum,
        int* boff, int* dstoff) {
    __shared__ int sh[128];
    int tx = threadIdx.x;
    int v = (tx < SCAN_NB) ? bsum[tx] : 0;
    sh[tx] = v;
    __syncthreads();
    for (int off = 1; off < 128; off <<= 1) {
        int t = (tx >= off) ? sh[tx - off] : 0;
        __syncthreads();
        sh[tx] += t;
        __syncthreads();
    }
    if (tx < SCAN_NB) boff[tx] = sh[tx] - v;
    if (tx == 0) dstoff[NN] = NE;
}

__global__ __launch_bounds__(256) void scan_final_k(const int* __restrict__ cnt,
        const int* __restrict__ boff, int* dstoff, int* cur) {
    __shared__ int sh[256];
    int tx = threadIdx.x;
    int i = blockIdx.x * 256 + tx;
    int v = (i < NN) ? cnt[i] : 0;
    sh[tx] = v;
    __syncthreads();
    for (int off = 1; off < 256; off <<= 1) {
        int t = (tx >= off) ? sh[tx - off] : 0;
        __syncthreads();
        sh[tx] += t;
        __syncthreads();
    }
    int excl = boff[blockIdx.x] + sh[tx] - v;
    if (i < NN) { dstoff[i] = excl; cur[i] = excl; }
}

__global__ __launch_bounds__(256) void scatter_k(const int* __restrict__ src,
        const int* __restrict__ dst, int* cur, int* __restrict__ src_d) {
    int e = blockIdx.x * 256 + threadIdx.x;
    if (e >= NE) return;
    int pd = atomicAdd(&cur[dst[e]], 1);
    src_d[pd] = src[e];
}

// ---------------------------------------------------------------------------
// K1: E[t, i*64+j] = sum_{e->t} dnorm[e,i] * h[src_e, j]
// ---------------------------------------------------------------------------
#define NWE 8192
__global__ __launch_bounds__(256) void edge_E_k(const int* __restrict__ src_d,
        const int* __restrict__ dstoff, const float* __restrict__ cemb,
        const float* __restrict__ h, float* __restrict__ E) {
    int gid  = blockIdx.x * 256 + threadIdx.x;
    int w    = gid >> 6;
    int lane = threadIdx.x & 63;
    long long t0 = (long long)w * NE / NWE;
    long long t1 = (long long)(w + 1) * NE / NWE;
    int lo = 0, hi = NN;
    while (lo < hi) { int mid = (lo + hi) >> 1; if (dstoff[mid] < t0) lo = mid + 1; else hi = mid; }
    int nlo = lo;
    lo = 0; hi = NN;
    while (lo < hi) { int mid = (lo + hi) >> 1; if (dstoff[mid] < t1) lo = mid + 1; else hi = mid; }
    int nhi = (w == NWE - 1) ? NN : lo;

    for (int n = nlo; n < nhi; n++) {
        float e0=0,e1=0,e2=0,e3=0,e4=0,e5=0,e6=0,e7=0;
        int p0 = dstoff[n], p1 = dstoff[n + 1];
        float4 na = *(const float4*)(cemb + (size_t)n * 8);
        float4 nb = *(const float4*)(cemb + (size_t)n * 8 + 4);
        for (int p = p0; p < p1; p++) {
            int s = src_d[p];
            float4 sa = *(const float4*)(cemb + (size_t)s * 8);
            float4 sb = *(const float4*)(cemb + (size_t)s * 8 + 4);
            float d0 = sa.x - na.x, d1 = sa.y - na.y, d2 = sa.z - na.z, d3 = sa.w - na.w;
            float d4 = sb.x - nb.x, d5 = sb.y - nb.y, d6 = sb.z - nb.z, d7 = sb.w - nb.w;
            float nn2 = d0*d0 + d1*d1 + d2*d2 + d3*d3 + d4*d4 + d5*d5 + d6*d6 + d7*d7;
            float inv = 1.f / fmaxf(sqrtf(nn2), 1e-12f);
            float hv = h[(size_t)s * 64 + lane];
            float hi2 = hv * inv;
            e0 = fmaf(d0, hi2, e0); e1 = fmaf(d1, hi2, e1);
            e2 = fmaf(d2, hi2, e2); e3 = fmaf(d3, hi2, e3);
            e4 = fmaf(d4, hi2, e4); e5 = fmaf(d5, hi2, e5);
            e6 = fmaf(d6, hi2, e6); e7 = fmaf(d7, hi2, e7);
        }
        float* ep = E + (size_t)n * 512 + lane;
        ep[0*64] = e0; ep[1*64] = e1; ep[2*64] = e2; ep[3*64] = e3;
        ep[4*64] = e4; ep[5*64] = e5; ep[6*64] = e6; ep[7*64] = e7;
    }
}

// ---------------------------------------------------------------------------
// K2: K-split finish GEMM. blockIdx.y = part p; computes
// P[p][n,k] = sum_{q in [p*128,(p+1)*128)} E[n,q] * W[q,k]
// 64-node x 64-col tile, 4x4/thread. 1564 blocks -> ~4 blocks/CU.
// ---------------------------------------------------------------------------
__global__ __launch_bounds__(256) void finish_gemm_part_k(const float* __restrict__ E,
        const float* __restrict__ W, float* __restrict__ P) {
    __shared__ float Et[64][68];   // [q_local][node_local]
    __shared__ float Wsh[64][64];  // [q_local][k]
    int n0 = blockIdx.x * 64;
    int part = blockIdx.y;
    int tx = threadIdx.x;
    int col0 = (tx & 15) * 4;
    int row0 = (tx >> 4) * 4;
    float acc[4][4] = {{0.f}};

    for (int c = 0; c < 2; c++) {
        __syncthreads();
        for (int t = tx; t < 4096; t += 256) {
            int r = t >> 6, q = t & 63;
            int n = n0 + r;
            Et[q][r] = (n < NN) ? E[(size_t)n * 512 + part * 128 + c * 64 + q] : 0.f;
        }
        for (int t = tx; t < 4096; t += 256)
            Wsh[t >> 6][t & 63] = W[(part * 2 + c) * 4096 + t];
        __syncthreads();
#pragma unroll 8
        for (int q = 0; q < 64; q++) {
            float4 a = *(const float4*)&Et[q][row0];
            float4 b = *(const float4*)&Wsh[q][col0];
            float a4[4] = {a.x, a.y, a.z, a.w};
            float b4[4] = {b.x, b.y, b.z, b.w};
#pragma unroll
            for (int r = 0; r < 4; r++)
#pragma unroll
                for (int cc = 0; cc < 4; cc++)
                    acc[r][cc] = fmaf(a4[r], b4[cc], acc[r][cc]);
        }
    }
    float* Pp = P + (size_t)part * NN * 64;
#pragma unroll
    for (int r = 0; r < 4; r++) {
        int n = n0 + row0 + r;
        if (n < NN)
            *(float4*)(Pp + (size_t)n * 64 + col0) =
                make_float4(acc[r][0], acc[r][1], acc[r][2], acc[r][3]);
    }
}

// ---------------------------------------------------------------------------
// K3: combine 4 partials -> agg; fused relu BN-stats.
// ---------------------------------------------------------------------------
__global__ __launch_bounds__(256) void combine_stats_k(const float* __restrict__ P,
        float* __restrict__ agg, float* sums, float* sumsq) {
    __shared__ float r1[16 * 64], r2[16 * 64];
    int tx = threadIdx.x;
    int idx0 = blockIdx.x * 256 + tx;
    int stride = gridDim.x * 256;      // float4 granularity
    const int n4 = NN * 16;            // NN*64/4
    int col0 = (tx & 15) * 4;
    float s1v[4] = {0.f}, s2v[4] = {0.f};
    for (int i4 = idx0; i4 < n4; i4 += stride) {
        float4 a = *(const float4*)(P + (size_t)i4 * 4);
        float4 b = *(const float4*)(P + (size_t)NN * 64 + (size_t)i4 * 4);
        float4 c = *(const float4*)(P + (size_t)2 * NN * 64 + (size_t)i4 * 4);
        float4 d = *(const float4*)(P + (size_t)3 * NN * 64 + (size_t)i4 * 4);
        float4 v = make_float4(a.x + b.x + c.x + d.x, a.y + b.y + c.y + d.y,
                               a.z + b.z + c.z + d.z, a.w + b.w + c.w + d.w);
        *(float4*)(agg + (size_t)i4 * 4) = v;
        float x0 = fmaxf(v.x, 0.f), x1 = fmaxf(v.y, 0.f);
        float x2 = fmaxf(v.z, 0.f), x3 = fmaxf(v.w, 0.f);
        s1v[0] += x0; s2v[0] += x0 * x0;
        s1v[1] += x1; s2v[1] += x1 * x1;
        s1v[2] += x2; s2v[2] += x2 * x2;
        s1v[3] += x3; s2v[3] += x3 * x3;
    }
    int grp = tx >> 4;
#pragma unroll
    for (int c = 0; c < 4; c++) {
        r1[grp * 64 + col0 + c] = s1v[c];
        r2[grp * 64 + col0 + c] = s2v[c];
    }
    __syncthreads();
    if (tx < 64) {
        float a = 0.f, b = 0.f;
#pragma unroll
        for (int g = 0; g < 16; g++) { a += r1[g * 64 + tx]; b += r2[g * 64 + tx]; }
        atomicAdd(&sums[tx], a);
        atomicAdd(&sumsq[tx], b);
    }
}

// ---------------------------------------------------------------------------
// K4: BN apply + shortcut + graph pooling
// ---------------------------------------------------------------------------
__global__ __launch_bounds__(256) void bn_apply_k(const float* agg,
        const float* __restrict__ h_old, const float* __restrict__ sums,
        const float* __restrict__ sumsq, const float* __restrict__ gamma,
        const float* __restrict__ beta, const int* __restrict__ gids,
        float* h_new, float* pooled, int shortcut) {
    __shared__ float pl[NG * 64];
    int tx = threadIdx.x;
    for (int t = tx; t < NG * 64; t += 256) pl[t] = 0.f;
    __syncthreads();

    int k = tx & 63;
    float mean = sums[k] * (1.f / NN);
    float var  = sumsq[k] * (1.f / NN) - mean * mean;
    float rstd = rsqrtf(var + 1e-5f);
    float g = gamma[k], b = beta[k];

    int idx0 = blockIdx.x * 256 + tx;
    int stride = gridDim.x * 256;
    for (int idx = idx0; idx < NN * 64; idx += stride) {
        int n = idx >> 6;
        float x = fmaxf(agg[idx], 0.f);
        float y = g * (x - mean) * rstd + b;
        if (shortcut) y += h_old[idx];
        h_new[idx] = y;
        atomicAdd(&pl[gids[n] * 64 + k], y);
    }
    __syncthreads();
    for (int t = tx; t < NG * 64; t += 256) {
        float v = pl[t];
        if (v != 0.f) atomicAdd(&pooled[t], v);
    }
}

// ---------------------------------------------------------------------------
// K5: classifier (single block)
// ---------------------------------------------------------------------------
__global__ __launch_bounds__(512) void classifier_k(const float* __restrict__ pooled,
        const float* __restrict__ cW1, const float* __restrict__ cb1,
        const float* __restrict__ cg1, const float* __restrict__ cbt1,
        const float* __restrict__ cW2, const float* __restrict__ cb2,
        float* logits) {
    __shared__ float P[NG * 64];
    __shared__ float H1[NG * 32];
    __shared__ float cmu[32], crs[32];
    int tx = threadIdx.x;
    for (int t = tx; t < NG * 64; t += 512) P[t] = pooled[t];
    __syncthreads();

    int gidx = tx >> 5;
    int c    = tx & 31;
    float acc = cb1[c];
#pragma unroll 16
    for (int j = 0; j < 64; j++) acc = fmaf(P[gidx * 64 + j], cW1[j * 32 + c], acc);
    H1[gidx * 32 + c] = acc;
    __syncthreads();

    if (tx < 32) {
        float mu = 0.f;
#pragma unroll
        for (int g2 = 0; g2 < NG; g2++) mu += H1[g2 * 32 + tx];
        mu *= (1.f / NG);
        float v = 0.f;
#pragma unroll
        for (int g2 = 0; g2 < NG; g2++) {
            float d = H1[g2 * 32 + tx] - mu;
            v += d * d;
        }
        v *= (1.f / NG);
        cmu[tx] = mu;
        crs[tx] = rsqrtf(v + 1e-5f);
    }
    __syncthreads();

    float h1 = fmaxf(cg1[c] * (H1[gidx * 32 + c] - cmu[c]) * crs[c] + cbt1[c], 0.f);
    __syncthreads();
    H1[gidx * 32 + c] = h1;
    __syncthreads();

    if (tx < NG * NC) {
        int gg = tx / NC, cls = tx % NC;
        float a2 = cb2[cls];
#pragma unroll
        for (int j = 0; j < 32; j++) a2 = fmaf(H1[gg * 32 + j], cW2[j * NC + cls], a2);
        logits[tx] += a2;
    }
}

// ---------------------------------------------------------------------------
extern "C" void kernel_launch(void* const* d_in, const int* in_sizes, int n_in,
                              void* d_out, int out_size, void* d_ws, size_t ws_size,
                              hipStream_t stream) {
    const float* feature = (const float*)d_in[0];
    const float* cemb    = (const float*)d_in[1];
    const int*   src     = (const int*)d_in[2];
    const int*   dst     = (const int*)d_in[3];
    const int*   gids    = (const int*)d_in[4];
    const float* W[3]    = {(const float*)d_in[5], (const float*)d_in[6], (const float*)d_in[7]};
    const float* gam[3]  = {(const float*)d_in[8], (const float*)d_in[10], (const float*)d_in[12]};
    const float* bet[3]  = {(const float*)d_in[9], (const float*)d_in[11], (const float*)d_in[13]};
    const float* cW1  = (const float*)d_in[14];
    const float* cb1  = (const float*)d_in[15];
    const float* cg1  = (const float*)d_in[16];
    const float* cbt1 = (const float*)d_in[17];
    const float* cW2  = (const float*)d_in[18];
    const float* cb2  = (const float*)d_in[19];
    float* out = (float*)d_out;

    // workspace layout (4-byte units)
    float* ws      = (float*)d_ws;
    float* E       = ws;                          // NN*512  = 12,800,000
    float* Pparts  = E + (size_t)NN * 512;        // 4*NN*64 = 6,400,000
    float* bufX    = Pparts + (size_t)4 * NN * 64;// NN*64
    float* bufY    = bufX + (size_t)NN * 64;      // NN*64
    float* sums    = bufY + (size_t)NN * 64;      // 64
    float* sumsq   = sums + 64;                   // 64
    float* pooled  = sumsq + 64;                  // 1024 (block reserved: 2048)
    int*   cnt     = (int*)(sums + 2048);         // NN
    int*   cur     = cnt + NN;                    // NN
    int*   dstoff  = cur + NN;                    // NN+1 (pad +8)
    int*   bsum    = dstoff + NN + 8;             // 128
    int*   boff    = bsum + 128;                  // 128
    int*   src_d   = boff + 128;                  // NE

    hipMemsetAsync(d_out, 0, (size_t)NG * NC * sizeof(float), stream);
    hipMemsetAsync(cnt, 0, NN * sizeof(int), stream);

    hist_k<<<(NE + 255) / 256, 256, 0, stream>>>(dst, cnt);
    scan_part_k<<<SCAN_NB, 256, 0, stream>>>(cnt, bsum);
    scan_mid_k<<<1, 128, 0, stream>>>(bsum, boff, dstoff);
    scan_final_k<<<SCAN_NB, 256, 0, stream>>>(cnt, boff, dstoff, cur);
    scatter_k<<<(NE + 255) / 256, 256, 0, stream>>>(src, dst, cur, src_d);

    const float* h_old = feature;
    float* bufs[2] = {bufX, bufY};
    for (int l = 0; l < 3; l++) {
        float* agg = bufs[l & 1];
        hipMemsetAsync(sums, 0, 2048 * sizeof(float), stream);

        edge_E_k<<<NWE / 4, 256, 0, stream>>>(src_d, dstoff, cemb, h_old, E);
        finish_gemm_part_k<<<dim3((NN + 63) / 64, 4), 256, 0, stream>>>(E, W[l], Pparts);
        combine_stats_k<<<512, 256, 0, stream>>>(Pparts, agg, sums, sumsq);
        bn_apply_k<<<256, 256, 0, stream>>>(agg, h_old, sums, sumsq, gam[l], bet[l],
                                            gids, agg, pooled, l > 0);
        classifier_k<<<1, 512, 0, stream>>>(pooled, cW1, cb1, cg1, cbt1, cW2, cb2, out);
        h_old = agg;
    }
}

// Round 6
// 590.838 us; speedup vs baseline: 1.4430x; 1.0615x over previous
//
#include <hip/hip_runtime.h>
#include <math.h>

#define NN 25000
#define NE 400000
#define HD 64
#define EMBD 8
#define NG 16
#define NC 10
#define SCAN_NB 98   // ceil(NN/256)

// ---------------------------------------------------------------------------
// Sort phase: dst-CSR (edge structure is layer-invariant).
// ---------------------------------------------------------------------------
__global__ __launch_bounds__(256) void hist_k(const int* __restrict__ dst, int* cnt) {
    int e = blockIdx.x * 256 + threadIdx.x;
    if (e < NE) atomicAdd(&cnt[dst[e]], 1);
}

__global__ __launch_bounds__(256) void scan_part_k(const int* __restrict__ cnt, int* bsum) {
    __shared__ int sh[256];
    int tx = threadIdx.x;
    int i = blockIdx.x * 256 + tx;
    sh[tx] = (i < NN) ? cnt[i] : 0;
    __syncthreads();
    for (int off = 128; off > 0; off >>= 1) {
        if (tx < off) sh[tx] += sh[tx + off];
        __syncthreads();
    }
    if (tx == 0) bsum[blockIdx.x] = sh[0];
}

__global__ __launch_bounds__(128) void scan_mid_k(const int* __restrict__ bsum,
        int* boff, int* dstoff) {
    __shared__ int sh[128];
    int tx = threadIdx.x;
    int v = (tx < SCAN_NB) ? bsum[tx] : 0;
    sh[tx] = v;
    __syncthreads();
    for (int off = 1; off < 128; off <<= 1) {
        int t = (tx >= off) ? sh[tx - off] : 0;
        __syncthreads();
        sh[tx] += t;
        __syncthreads();
    }
    if (tx < SCAN_NB) boff[tx] = sh[tx] - v;
    if (tx == 0) dstoff[NN] = NE;
}

__global__ __launch_bounds__(256) void scan_final_k(const int* __restrict__ cnt,
        const int* __restrict__ boff, int* dstoff, int* cur) {
    __shared__ int sh[256];
    int tx = threadIdx.x;
    int i = blockIdx.x * 256 + tx;
    int v = (i < NN) ? cnt[i] : 0;
    sh[tx] = v;
    __syncthreads();
    for (int off = 1; off < 256; off <<= 1) {
        int t = (tx >= off) ? sh[tx - off] : 0;
        __syncthreads();
        sh[tx] += t;
        __syncthreads();
    }
    int excl = boff[blockIdx.x] + sh[tx] - v;
    if (i < NN) { dstoff[i] = excl; cur[i] = excl; }
}

// scatter: place src at dst-sorted slot AND precompute normalized direction
// there (layer-invariant -> done once, not 3x).
__global__ __launch_bounds__(256) void scatter_k(const int* __restrict__ src,
        const int* __restrict__ dst, const float* __restrict__ c,
        int* cur, int* __restrict__ src_d, float* __restrict__ dnorm_d) {
    int e = blockIdx.x * 256 + threadIdx.x;
    if (e >= NE) return;
    int s = src[e], t = dst[e];
    int pd = atomicAdd(&cur[t], 1);
    src_d[pd] = s;
    float4 sa = *(const float4*)(c + (size_t)s * 8);
    float4 sb = *(const float4*)(c + (size_t)s * 8 + 4);
    float4 na = *(const float4*)(c + (size_t)t * 8);
    float4 nb = *(const float4*)(c + (size_t)t * 8 + 4);
    float d0 = sa.x - na.x, d1 = sa.y - na.y, d2 = sa.z - na.z, d3 = sa.w - na.w;
    float d4 = sb.x - nb.x, d5 = sb.y - nb.y, d6 = sb.z - nb.z, d7 = sb.w - nb.w;
    float nn2 = d0*d0 + d1*d1 + d2*d2 + d3*d3 + d4*d4 + d5*d5 + d6*d6 + d7*d7;
    float inv = 1.f / fmaxf(sqrtf(nn2), 1e-12f);
    *(float4*)(dnorm_d + (size_t)pd * 8)     = make_float4(d0*inv, d1*inv, d2*inv, d3*inv);
    *(float4*)(dnorm_d + (size_t)pd * 8 + 4) = make_float4(d4*inv, d5*inv, d6*inv, d7*inv);
}

// ---------------------------------------------------------------------------
// K1: E[t, i*64+j] = sum_{e->t} dnorm[e,i] * h[src_e, j]
// Inner loop now: 1 idx load + 2 broadcast float4 + 1 h gather + 8 FMA.
// ---------------------------------------------------------------------------
#define NWE 8192
__global__ __launch_bounds__(256) void edge_E_k(const int* __restrict__ src_d,
        const int* __restrict__ dstoff, const float* __restrict__ dnorm_d,
        const float* __restrict__ h, float* __restrict__ E) {
    int gid  = blockIdx.x * 256 + threadIdx.x;
    int w    = gid >> 6;
    int lane = threadIdx.x & 63;
    long long t0 = (long long)w * NE / NWE;
    long long t1 = (long long)(w + 1) * NE / NWE;
    int lo = 0, hi = NN;
    while (lo < hi) { int mid = (lo + hi) >> 1; if (dstoff[mid] < t0) lo = mid + 1; else hi = mid; }
    int nlo = lo;
    lo = 0; hi = NN;
    while (lo < hi) { int mid = (lo + hi) >> 1; if (dstoff[mid] < t1) lo = mid + 1; else hi = mid; }
    int nhi = (w == NWE - 1) ? NN : lo;

    for (int n = nlo; n < nhi; n++) {
        float e0=0,e1=0,e2=0,e3=0,e4=0,e5=0,e6=0,e7=0;
        int p0 = dstoff[n], p1 = dstoff[n + 1];
        for (int p = p0; p < p1; p++) {
            int s = src_d[p];
            float4 dA = *(const float4*)(dnorm_d + (size_t)p * 8);
            float4 dB = *(const float4*)(dnorm_d + (size_t)p * 8 + 4);
            float hv = h[(size_t)s * 64 + lane];
            e0 = fmaf(dA.x, hv, e0); e1 = fmaf(dA.y, hv, e1);
            e2 = fmaf(dA.z, hv, e2); e3 = fmaf(dA.w, hv, e3);
            e4 = fmaf(dB.x, hv, e4); e5 = fmaf(dB.y, hv, e5);
            e6 = fmaf(dB.z, hv, e6); e7 = fmaf(dB.w, hv, e7);
        }
        float* ep = E + (size_t)n * 512 + lane;
        ep[0*64] = e0; ep[1*64] = e1; ep[2*64] = e2; ep[3*64] = e3;
        ep[4*64] = e4; ep[5*64] = e5; ep[6*64] = e6; ep[7*64] = e7;
    }
}

// ---------------------------------------------------------------------------
// K2: K-split finish GEMM. blockIdx.y = part p; computes
// P[p][n,k] = sum_{q in [p*128,(p+1)*128)} E[n,q] * W[q,k]
// ---------------------------------------------------------------------------
__global__ __launch_bounds__(256) void finish_gemm_part_k(const float* __restrict__ E,
        const float* __restrict__ W, float* __restrict__ P) {
    __shared__ float Et[64][68];
    __shared__ float Wsh[64][64];
    int n0 = blockIdx.x * 64;
    int part = blockIdx.y;
    int tx = threadIdx.x;
    int col0 = (tx & 15) * 4;
    int row0 = (tx >> 4) * 4;
    float acc[4][4] = {{0.f}};

    for (int c = 0; c < 2; c++) {
        __syncthreads();
        for (int t = tx; t < 4096; t += 256) {
            int r = t >> 6, q = t & 63;
            int n = n0 + r;
            Et[q][r] = (n < NN) ? E[(size_t)n * 512 + part * 128 + c * 64 + q] : 0.f;
        }
        for (int t = tx; t < 4096; t += 256)
            Wsh[t >> 6][t & 63] = W[(part * 2 + c) * 4096 + t];
        __syncthreads();
#pragma unroll 8
        for (int q = 0; q < 64; q++) {
            float4 a = *(const float4*)&Et[q][row0];
            float4 b = *(const float4*)&Wsh[q][col0];
            float a4[4] = {a.x, a.y, a.z, a.w};
            float b4[4] = {b.x, b.y, b.z, b.w};
#pragma unroll
            for (int r = 0; r < 4; r++)
#pragma unroll
                for (int cc = 0; cc < 4; cc++)
                    acc[r][cc] = fmaf(a4[r], b4[cc], acc[r][cc]);
        }
    }
    float* Pp = P + (size_t)part * NN * 64;
#pragma unroll
    for (int r = 0; r < 4; r++) {
        int n = n0 + row0 + r;
        if (n < NN)
            *(float4*)(Pp + (size_t)n * 64 + col0) =
                make_float4(acc[r][0], acc[r][1], acc[r][2], acc[r][3]);
    }
}

// ---------------------------------------------------------------------------
// K3: combine 4 partials -> agg; fused relu BN-stats.
// ---------------------------------------------------------------------------
__global__ __launch_bounds__(256) void combine_stats_k(const float* __restrict__ P,
        float* __restrict__ agg, float* sums, float* sumsq) {
    __shared__ float r1[16 * 64], r2[16 * 64];
    int tx = threadIdx.x;
    int idx0 = blockIdx.x * 256 + tx;
    int stride = gridDim.x * 256;
    const int n4 = NN * 16;
    int col0 = (tx & 15) * 4;
    float s1v[4] = {0.f}, s2v[4] = {0.f};
    for (int i4 = idx0; i4 < n4; i4 += stride) {
        float4 a = *(const float4*)(P + (size_t)i4 * 4);
        float4 b = *(const float4*)(P + (size_t)NN * 64 + (size_t)i4 * 4);
        float4 c = *(const float4*)(P + (size_t)2 * NN * 64 + (size_t)i4 * 4);
        float4 d = *(const float4*)(P + (size_t)3 * NN * 64 + (size_t)i4 * 4);
        float4 v = make_float4(a.x + b.x + c.x + d.x, a.y + b.y + c.y + d.y,
                               a.z + b.z + c.z + d.z, a.w + b.w + c.w + d.w);
        *(float4*)(agg + (size_t)i4 * 4) = v;
        float x0 = fmaxf(v.x, 0.f), x1 = fmaxf(v.y, 0.f);
        float x2 = fmaxf(v.z, 0.f), x3 = fmaxf(v.w, 0.f);
        s1v[0] += x0; s2v[0] += x0 * x0;
        s1v[1] += x1; s2v[1] += x1 * x1;
        s1v[2] += x2; s2v[2] += x2 * x2;
        s1v[3] += x3; s2v[3] += x3 * x3;
    }
    int grp = tx >> 4;
#pragma unroll
    for (int c = 0; c < 4; c++) {
        r1[grp * 64 + col0 + c] = s1v[c];
        r2[grp * 64 + col0 + c] = s2v[c];
    }
    __syncthreads();
    if (tx < 64) {
        float a = 0.f, b = 0.f;
#pragma unroll
        for (int g = 0; g < 16; g++) { a += r1[g * 64 + tx]; b += r2[g * 64 + tx]; }
        atomicAdd(&sums[tx], a);
        atomicAdd(&sumsq[tx], b);
    }
}

// ---------------------------------------------------------------------------
// K4: BN apply + shortcut + graph pooling
// ---------------------------------------------------------------------------
__global__ __launch_bounds__(256) void bn_apply_k(const float* agg,
        const float* __restrict__ h_old, const float* __restrict__ sums,
        const float* __restrict__ sumsq, const float* __restrict__ gamma,
        const float* __restrict__ beta, const int* __restrict__ gids,
        float* h_new, float* pooled, int shortcut) {
    __shared__ float pl[NG * 64];
    int tx = threadIdx.x;
    for (int t = tx; t < NG * 64; t += 256) pl[t] = 0.f;
    __syncthreads();

    int k = tx & 63;
    float mean = sums[k] * (1.f / NN);
    float var  = sumsq[k] * (1.f / NN) - mean * mean;
    float rstd = rsqrtf(var + 1e-5f);
    float g = gamma[k], b = beta[k];

    int idx0 = blockIdx.x * 256 + tx;
    int stride = gridDim.x * 256;
    for (int idx = idx0; idx < NN * 64; idx += stride) {
        int n = idx >> 6;
        float x = fmaxf(agg[idx], 0.f);
        float y = g * (x - mean) * rstd + b;
        if (shortcut) y += h_old[idx];
        h_new[idx] = y;
        atomicAdd(&pl[gids[n] * 64 + k], y);
    }
    __syncthreads();
    for (int t = tx; t < NG * 64; t += 256) {
        float v = pl[t];
        if (v != 0.f) atomicAdd(&pooled[t], v);
    }
}

// ---------------------------------------------------------------------------
// K5: classifier (single block)
// ---------------------------------------------------------------------------
__global__ __launch_bounds__(512) void classifier_k(const float* __restrict__ pooled,
        const float* __restrict__ cW1, const float* __restrict__ cb1,
        const float* __restrict__ cg1, const float* __restrict__ cbt1,
        const float* __restrict__ cW2, const float* __restrict__ cb2,
        float* logits) {
    __shared__ float P[NG * 64];
    __shared__ float H1[NG * 32];
    __shared__ float cmu[32], crs[32];
    int tx = threadIdx.x;
    for (int t = tx; t < NG * 64; t += 512) P[t] = pooled[t];
    __syncthreads();

    int gidx = tx >> 5;
    int c    = tx & 31;
    float acc = cb1[c];
#pragma unroll 16
    for (int j = 0; j < 64; j++) acc = fmaf(P[gidx * 64 + j], cW1[j * 32 + c], acc);
    H1[gidx * 32 + c] = acc;
    __syncthreads();

    if (tx < 32) {
        float mu = 0.f;
#pragma unroll
        for (int g2 = 0; g2 < NG; g2++) mu += H1[g2 * 32 + tx];
        mu *= (1.f / NG);
        float v = 0.f;
#pragma unroll
        for (int g2 = 0; g2 < NG; g2++) {
            float d = H1[g2 * 32 + tx] - mu;
            v += d * d;
        }
        v *= (1.f / NG);
        cmu[tx] = mu;
        crs[tx] = rsqrtf(v + 1e-5f);
    }
    __syncthreads();

    float h1 = fmaxf(cg1[c] * (H1[gidx * 32 + c] - cmu[c]) * crs[c] + cbt1[c], 0.f);
    __syncthreads();
    H1[gidx * 32 + c] = h1;
    __syncthreads();

    if (tx < NG * NC) {
        int gg = tx / NC, cls = tx % NC;
        float a2 = cb2[cls];
#pragma unroll
        for (int j = 0; j < 32; j++) a2 = fmaf(H1[gg * 32 + j], cW2[j * NC + cls], a2);
        logits[tx] += a2;
    }
}

// ---------------------------------------------------------------------------
extern "C" void kernel_launch(void* const* d_in, const int* in_sizes, int n_in,
                              void* d_out, int out_size, void* d_ws, size_t ws_size,
                              hipStream_t stream) {
    const float* feature = (const float*)d_in[0];
    const float* cemb    = (const float*)d_in[1];
    const int*   src     = (const int*)d_in[2];
    const int*   dst     = (const int*)d_in[3];
    const int*   gids    = (const int*)d_in[4];
    const float* W[3]    = {(const float*)d_in[5], (const float*)d_in[6], (const float*)d_in[7]};
    const float* gam[3]  = {(const float*)d_in[8], (const float*)d_in[10], (const float*)d_in[12]};
    const float* bet[3]  = {(const float*)d_in[9], (const float*)d_in[11], (const float*)d_in[13]};
    const float* cW1  = (const float*)d_in[14];
    const float* cb1  = (const float*)d_in[15];
    const float* cg1  = (const float*)d_in[16];
    const float* cbt1 = (const float*)d_in[17];
    const float* cW2  = (const float*)d_in[18];
    const float* cb2  = (const float*)d_in[19];
    float* out = (float*)d_out;

    // workspace layout (4-byte units)
    float* ws      = (float*)d_ws;
    float* E       = ws;                           // NN*512  = 12,800,000
    float* Pparts  = E + (size_t)NN * 512;         // 4*NN*64 = 6,400,000
    float* dnorm_d = Pparts + (size_t)4 * NN * 64; // NE*8    = 3,200,000
    float* bufX    = dnorm_d + (size_t)NE * 8;     // NN*64
    float* bufY    = bufX + (size_t)NN * 64;       // NN*64
    float* sums    = bufY + (size_t)NN * 64;       // 64
    float* sumsq   = sums + 64;                    // 64
    float* pooled  = sumsq + 64;                   // 1024 (block reserved: 2048)
    int*   cnt     = (int*)(sums + 2048);          // NN
    int*   cur     = cnt + NN;                     // NN
    int*   dstoff  = cur + NN;                     // NN+1 (pad +8)
    int*   bsum    = dstoff + NN + 8;              // 128
    int*   boff    = bsum + 128;                   // 128
    int*   src_d   = boff + 128;                   // NE

    hipMemsetAsync(d_out, 0, (size_t)NG * NC * sizeof(float), stream);
    hipMemsetAsync(cnt, 0, NN * sizeof(int), stream);

    hist_k<<<(NE + 255) / 256, 256, 0, stream>>>(dst, cnt);
    scan_part_k<<<SCAN_NB, 256, 0, stream>>>(cnt, bsum);
    scan_mid_k<<<1, 128, 0, stream>>>(bsum, boff, dstoff);
    scan_final_k<<<SCAN_NB, 256, 0, stream>>>(cnt, boff, dstoff, cur);
    scatter_k<<<(NE + 255) / 256, 256, 0, stream>>>(src, dst, cemb, cur, src_d, dnorm_d);

    const float* h_old = feature;
    float* bufs[2] = {bufX, bufY};
    for (int l = 0; l < 3; l++) {
        float* agg = bufs[l & 1];
        hipMemsetAsync(sums, 0, 2048 * sizeof(float), stream);

        edge_E_k<<<NWE / 4, 256, 0, stream>>>(src_d, dstoff, dnorm_d, h_old, E);
        finish_gemm_part_k<<<dim3((NN + 63) / 64, 4), 256, 0, stream>>>(E, W[l], Pparts);
        combine_stats_k<<<512, 256, 0, stream>>>(Pparts, agg, sums, sumsq);
        bn_apply_k<<<256, 256, 0, stream>>>(agg, h_old, sums, sumsq, gam[l], bet[l],
                                            gids, agg, pooled, l > 0);
        classifier_k<<<1, 512, 0, stream>>>(pooled, cW1, cb1, cg1, cbt1, cW2, cb2, out);
        h_old = agg;
    }
}

// Round 7
// 581.185 us; speedup vs baseline: 1.4670x; 1.0166x over previous
//
#include <hip/hip_runtime.h>
#include <math.h>

#define NN 25000
#define NE 400000
#define HD 64
#define EMBD 8
#define NG 16
#define NC 10
#define SCAN_NB 98   // ceil(NN/256)

// ---------------------------------------------------------------------------
// Sort phase: dst-CSR (edge structure is layer-invariant).
// ---------------------------------------------------------------------------
__global__ __launch_bounds__(256) void hist_k(const int* __restrict__ dst, int* cnt) {
    int e = blockIdx.x * 256 + threadIdx.x;
    if (e < NE) atomicAdd(&cnt[dst[e]], 1);
}

__global__ __launch_bounds__(256) void scan_part_k(const int* __restrict__ cnt, int* bsum) {
    __shared__ int sh[256];
    int tx = threadIdx.x;
    int i = blockIdx.x * 256 + tx;
    sh[tx] = (i < NN) ? cnt[i] : 0;
    __syncthreads();
    for (int off = 128; off > 0; off >>= 1) {
        if (tx < off) sh[tx] += sh[tx + off];
        __syncthreads();
    }
    if (tx == 0) bsum[blockIdx.x] = sh[0];
}

__global__ __launch_bounds__(128) void scan_mid_k(const int* __restrict__ bsum,
        int* boff, int* dstoff) {
    __shared__ int sh[128];
    int tx = threadIdx.x;
    int v = (tx < SCAN_NB) ? bsum[tx] : 0;
    sh[tx] = v;
    __syncthreads();
    for (int off = 1; off < 128; off <<= 1) {
        int t = (tx >= off) ? sh[tx - off] : 0;
        __syncthreads();
        sh[tx] += t;
        __syncthreads();
    }
    if (tx < SCAN_NB) boff[tx] = sh[tx] - v;
    if (tx == 0) dstoff[NN] = NE;
}

__global__ __launch_bounds__(256) void scan_final_k(const int* __restrict__ cnt,
        const int* __restrict__ boff, int* dstoff, int* cur) {
    __shared__ int sh[256];
    int tx = threadIdx.x;
    int i = blockIdx.x * 256 + tx;
    int v = (i < NN) ? cnt[i] : 0;
    sh[tx] = v;
    __syncthreads();
    for (int off = 1; off < 256; off <<= 1) {
        int t = (tx >= off) ? sh[tx - off] : 0;
        __syncthreads();
        sh[tx] += t;
        __syncthreads();
    }
    int excl = boff[blockIdx.x] + sh[tx] - v;
    if (i < NN) { dstoff[i] = excl; cur[i] = excl; }
}

// scatter: place src at dst-sorted slot AND precompute normalized direction.
__global__ __launch_bounds__(256) void scatter_k(const int* __restrict__ src,
        const int* __restrict__ dst, const float* __restrict__ c,
        int* cur, int* __restrict__ src_d, float* __restrict__ dnorm_d) {
    int e = blockIdx.x * 256 + threadIdx.x;
    if (e >= NE) return;
    int s = src[e], t = dst[e];
    int pd = atomicAdd(&cur[t], 1);
    src_d[pd] = s;
    float4 sa = *(const float4*)(c + (size_t)s * 8);
    float4 sb = *(const float4*)(c + (size_t)s * 8 + 4);
    float4 na = *(const float4*)(c + (size_t)t * 8);
    float4 nb = *(const float4*)(c + (size_t)t * 8 + 4);
    float d0 = sa.x - na.x, d1 = sa.y - na.y, d2 = sa.z - na.z, d3 = sa.w - na.w;
    float d4 = sb.x - nb.x, d5 = sb.y - nb.y, d6 = sb.z - nb.z, d7 = sb.w - nb.w;
    float nn2 = d0*d0 + d1*d1 + d2*d2 + d3*d3 + d4*d4 + d5*d5 + d6*d6 + d7*d7;
    float inv = 1.f / fmaxf(sqrtf(nn2), 1e-12f);
    *(float4*)(dnorm_d + (size_t)pd * 8)     = make_float4(d0*inv, d1*inv, d2*inv, d3*inv);
    *(float4*)(dnorm_d + (size_t)pd * 8 + 4) = make_float4(d4*inv, d5*inv, d6*inv, d7*inv);
}

// ---------------------------------------------------------------------------
// K1: E[t, i*64+j] = sum_{e->t} dnorm[e,i] * h[src_e, j]
// 4-deep unroll: 4 independent h-gathers in flight per iteration.
// ---------------------------------------------------------------------------
#define NWE 8192
__global__ __launch_bounds__(256) void edge_E_k(const int* __restrict__ src_d,
        const int* __restrict__ dstoff, const float* __restrict__ dnorm_d,
        const float* __restrict__ h, float* __restrict__ E) {
    int gid  = blockIdx.x * 256 + threadIdx.x;
    int w    = gid >> 6;
    int lane = threadIdx.x & 63;
    long long t0 = (long long)w * NE / NWE;
    long long t1 = (long long)(w + 1) * NE / NWE;
    int lo = 0, hi = NN;
    while (lo < hi) { int mid = (lo + hi) >> 1; if (dstoff[mid] < t0) lo = mid + 1; else hi = mid; }
    int nlo = lo;
    lo = 0; hi = NN;
    while (lo < hi) { int mid = (lo + hi) >> 1; if (dstoff[mid] < t1) lo = mid + 1; else hi = mid; }
    int nhi = (w == NWE - 1) ? NN : lo;

    for (int n = nlo; n < nhi; n++) {
        float e0=0,e1=0,e2=0,e3=0,e4=0,e5=0,e6=0,e7=0;
        int p0 = dstoff[n], p1 = dstoff[n + 1];
        int p = p0;
        for (; p + 3 < p1; p += 4) {
            // issue all independent loads first
            int s0 = src_d[p], s1 = src_d[p+1], s2 = src_d[p+2], s3 = src_d[p+3];
            float hv0 = h[(size_t)s0 * 64 + lane];
            float hv1 = h[(size_t)s1 * 64 + lane];
            float hv2 = h[(size_t)s2 * 64 + lane];
            float hv3 = h[(size_t)s3 * 64 + lane];
            float4 dA0 = *(const float4*)(dnorm_d + (size_t)p * 8);
            float4 dB0 = *(const float4*)(dnorm_d + (size_t)p * 8 + 4);
            float4 dA1 = *(const float4*)(dnorm_d + (size_t)(p+1) * 8);
            float4 dB1 = *(const float4*)(dnorm_d + (size_t)(p+1) * 8 + 4);
            float4 dA2 = *(const float4*)(dnorm_d + (size_t)(p+2) * 8);
            float4 dB2 = *(const float4*)(dnorm_d + (size_t)(p+2) * 8 + 4);
            float4 dA3 = *(const float4*)(dnorm_d + (size_t)(p+3) * 8);
            float4 dB3 = *(const float4*)(dnorm_d + (size_t)(p+3) * 8 + 4);
            e0 = fmaf(dA0.x, hv0, e0); e1 = fmaf(dA0.y, hv0, e1);
            e2 = fmaf(dA0.z, hv0, e2); e3 = fmaf(dA0.w, hv0, e3);
            e4 = fmaf(dB0.x, hv0, e4); e5 = fmaf(dB0.y, hv0, e5);
            e6 = fmaf(dB0.z, hv0, e6); e7 = fmaf(dB0.w, hv0, e7);
            e0 = fmaf(dA1.x, hv1, e0); e1 = fmaf(dA1.y, hv1, e1);
            e2 = fmaf(dA1.z, hv1, e2); e3 = fmaf(dA1.w, hv1, e3);
            e4 = fmaf(dB1.x, hv1, e4); e5 = fmaf(dB1.y, hv1, e5);
            e6 = fmaf(dB1.z, hv1, e6); e7 = fmaf(dB1.w, hv1, e7);
            e0 = fmaf(dA2.x, hv2, e0); e1 = fmaf(dA2.y, hv2, e1);
            e2 = fmaf(dA2.z, hv2, e2); e3 = fmaf(dA2.w, hv2, e3);
            e4 = fmaf(dB2.x, hv2, e4); e5 = fmaf(dB2.y, hv2, e5);
            e6 = fmaf(dB2.z, hv2, e6); e7 = fmaf(dB2.w, hv2, e7);
            e0 = fmaf(dA3.x, hv3, e0); e1 = fmaf(dA3.y, hv3, e1);
            e2 = fmaf(dA3.z, hv3, e2); e3 = fmaf(dA3.w, hv3, e3);
            e4 = fmaf(dB3.x, hv3, e4); e5 = fmaf(dB3.y, hv3, e5);
            e6 = fmaf(dB3.z, hv3, e6); e7 = fmaf(dB3.w, hv3, e7);
        }
        for (; p < p1; p++) {
            int s = src_d[p];
            float hv = h[(size_t)s * 64 + lane];
            float4 dA = *(const float4*)(dnorm_d + (size_t)p * 8);
            float4 dB = *(const float4*)(dnorm_d + (size_t)p * 8 + 4);
            e0 = fmaf(dA.x, hv, e0); e1 = fmaf(dA.y, hv, e1);
            e2 = fmaf(dA.z, hv, e2); e3 = fmaf(dA.w, hv, e3);
            e4 = fmaf(dB.x, hv, e4); e5 = fmaf(dB.y, hv, e5);
            e6 = fmaf(dB.z, hv, e6); e7 = fmaf(dB.w, hv, e7);
        }
        float* ep = E + (size_t)n * 512 + lane;
        ep[0*64] = e0; ep[1*64] = e1; ep[2*64] = e2; ep[3*64] = e3;
        ep[4*64] = e4; ep[5*64] = e5; ep[6*64] = e6; ep[7*64] = e7;
    }
}

// ---------------------------------------------------------------------------
// K2: K-split finish GEMM (4 parts of K=128).
// ---------------------------------------------------------------------------
__global__ __launch_bounds__(256) void finish_gemm_part_k(const float* __restrict__ E,
        const float* __restrict__ W, float* __restrict__ P) {
    __shared__ float Et[64][68];
    __shared__ float Wsh[64][64];
    int n0 = blockIdx.x * 64;
    int part = blockIdx.y;
    int tx = threadIdx.x;
    int col0 = (tx & 15) * 4;
    int row0 = (tx >> 4) * 4;
    float acc[4][4] = {{0.f}};

    for (int c = 0; c < 2; c++) {
        __syncthreads();
        for (int t = tx; t < 4096; t += 256) {
            int r = t >> 6, q = t & 63;
            int n = n0 + r;
            Et[q][r] = (n < NN) ? E[(size_t)n * 512 + part * 128 + c * 64 + q] : 0.f;
        }
        for (int t = tx; t < 4096; t += 256)
            Wsh[t >> 6][t & 63] = W[(part * 2 + c) * 4096 + t];
        __syncthreads();
#pragma unroll 8
        for (int q = 0; q < 64; q++) {
            float4 a = *(const float4*)&Et[q][row0];
            float4 b = *(const float4*)&Wsh[q][col0];
            float a4[4] = {a.x, a.y, a.z, a.w};
            float b4[4] = {b.x, b.y, b.z, b.w};
#pragma unroll
            for (int r = 0; r < 4; r++)
#pragma unroll
                for (int cc = 0; cc < 4; cc++)
                    acc[r][cc] = fmaf(a4[r], b4[cc], acc[r][cc]);
        }
    }
    float* Pp = P + (size_t)part * NN * 64;
#pragma unroll
    for (int r = 0; r < 4; r++) {
        int n = n0 + row0 + r;
        if (n < NN)
            *(float4*)(Pp + (size_t)n * 64 + col0) =
                make_float4(acc[r][0], acc[r][1], acc[r][2], acc[r][3]);
    }
}

// ---------------------------------------------------------------------------
// K3: combine 4 partials -> agg; fused relu BN-stats.
// ---------------------------------------------------------------------------
__global__ __launch_bounds__(256) void combine_stats_k(const float* __restrict__ P,
        float* __restrict__ agg, float* sums, float* sumsq) {
    __shared__ float r1[16 * 64], r2[16 * 64];
    int tx = threadIdx.x;
    int idx0 = blockIdx.x * 256 + tx;
    int stride = gridDim.x * 256;
    const int n4 = NN * 16;
    int col0 = (tx & 15) * 4;
    float s1v[4] = {0.f}, s2v[4] = {0.f};
    for (int i4 = idx0; i4 < n4; i4 += stride) {
        float4 a = *(const float4*)(P + (size_t)i4 * 4);
        float4 b = *(const float4*)(P + (size_t)NN * 64 + (size_t)i4 * 4);
        float4 c = *(const float4*)(P + (size_t)2 * NN * 64 + (size_t)i4 * 4);
        float4 d = *(const float4*)(P + (size_t)3 * NN * 64 + (size_t)i4 * 4);
        float4 v = make_float4(a.x + b.x + c.x + d.x, a.y + b.y + c.y + d.y,
                               a.z + b.z + c.z + d.z, a.w + b.w + c.w + d.w);
        *(float4*)(agg + (size_t)i4 * 4) = v;
        float x0 = fmaxf(v.x, 0.f), x1 = fmaxf(v.y, 0.f);
        float x2 = fmaxf(v.z, 0.f), x3 = fmaxf(v.w, 0.f);
        s1v[0] += x0; s2v[0] += x0 * x0;
        s1v[1] += x1; s2v[1] += x1 * x1;
        s1v[2] += x2; s2v[2] += x2 * x2;
        s1v[3] += x3; s2v[3] += x3 * x3;
    }
    int grp = tx >> 4;
#pragma unroll
    for (int c = 0; c < 4; c++) {
        r1[grp * 64 + col0 + c] = s1v[c];
        r2[grp * 64 + col0 + c] = s2v[c];
    }
    __syncthreads();
    if (tx < 64) {
        float a = 0.f, b = 0.f;
#pragma unroll
        for (int g = 0; g < 16; g++) { a += r1[g * 64 + tx]; b += r2[g * 64 + tx]; }
        atomicAdd(&sums[tx], a);
        atomicAdd(&sumsq[tx], b);
    }
}

// ---------------------------------------------------------------------------
// K4: BN apply + shortcut + graph pooling
// ---------------------------------------------------------------------------
__global__ __launch_bounds__(256) void bn_apply_k(const float* agg,
        const float* __restrict__ h_old, const float* __restrict__ sums,
        const float* __restrict__ sumsq, const float* __restrict__ gamma,
        const float* __restrict__ beta, const int* __restrict__ gids,
        float* h_new, float* pooled, int shortcut) {
    __shared__ float pl[NG * 64];
    int tx = threadIdx.x;
    for (int t = tx; t < NG * 64; t += 256) pl[t] = 0.f;
    __syncthreads();

    int k = tx & 63;
    float mean = sums[k] * (1.f / NN);
    float var  = sumsq[k] * (1.f / NN) - mean * mean;
    float rstd = rsqrtf(var + 1e-5f);
    float g = gamma[k], b = beta[k];

    int idx0 = blockIdx.x * 256 + tx;
    int stride = gridDim.x * 256;
    for (int idx = idx0; idx < NN * 64; idx += stride) {
        int n = idx >> 6;
        float x = fmaxf(agg[idx], 0.f);
        float y = g * (x - mean) * rstd + b;
        if (shortcut) y += h_old[idx];
        h_new[idx] = y;
        atomicAdd(&pl[gids[n] * 64 + k], y);
    }
    __syncthreads();
    for (int t = tx; t < NG * 64; t += 256) {
        float v = pl[t];
        if (v != 0.f) atomicAdd(&pooled[t], v);
    }
}

// ---------------------------------------------------------------------------
// K5: classifier (single block)
// ---------------------------------------------------------------------------
__global__ __launch_bounds__(512) void classifier_k(const float* __restrict__ pooled,
        const float* __restrict__ cW1, const float* __restrict__ cb1,
        const float* __restrict__ cg1, const float* __restrict__ cbt1,
        const float* __restrict__ cW2, const float* __restrict__ cb2,
        float* logits) {
    __shared__ float P[NG * 64];
    __shared__ float H1[NG * 32];
    __shared__ float cmu[32], crs[32];
    int tx = threadIdx.x;
    for (int t = tx; t < NG * 64; t += 512) P[t] = pooled[t];
    __syncthreads();

    int gidx = tx >> 5;
    int c    = tx & 31;
    float acc = cb1[c];
#pragma unroll 16
    for (int j = 0; j < 64; j++) acc = fmaf(P[gidx * 64 + j], cW1[j * 32 + c], acc);
    H1[gidx * 32 + c] = acc;
    __syncthreads();

    if (tx < 32) {
        float mu = 0.f;
#pragma unroll
        for (int g2 = 0; g2 < NG; g2++) mu += H1[g2 * 32 + tx];
        mu *= (1.f / NG);
        float v = 0.f;
#pragma unroll
        for (int g2 = 0; g2 < NG; g2++) {
            float d = H1[g2 * 32 + tx] - mu;
            v += d * d;
        }
        v *= (1.f / NG);
        cmu[tx] = mu;
        crs[tx] = rsqrtf(v + 1e-5f);
    }
    __syncthreads();

    float h1 = fmaxf(cg1[c] * (H1[gidx * 32 + c] - cmu[c]) * crs[c] + cbt1[c], 0.f);
    __syncthreads();
    H1[gidx * 32 + c] = h1;
    __syncthreads();

    if (tx < NG * NC) {
        int gg = tx / NC, cls = tx % NC;
        float a2 = cb2[cls];
#pragma unroll
        for (int j = 0; j < 32; j++) a2 = fmaf(H1[gg * 32 + j], cW2[j * NC + cls], a2);
        logits[tx] += a2;
    }
}

// ---------------------------------------------------------------------------
extern "C" void kernel_launch(void* const* d_in, const int* in_sizes, int n_in,
                              void* d_out, int out_size, void* d_ws, size_t ws_size,
                              hipStream_t stream) {
    const float* feature = (const float*)d_in[0];
    const float* cemb    = (const float*)d_in[1];
    const int*   src     = (const int*)d_in[2];
    const int*   dst     = (const int*)d_in[3];
    const int*   gids    = (const int*)d_in[4];
    const float* W[3]    = {(const float*)d_in[5], (const float*)d_in[6], (const float*)d_in[7]};
    const float* gam[3]  = {(const float*)d_in[8], (const float*)d_in[10], (const float*)d_in[12]};
    const float* bet[3]  = {(const float*)d_in[9], (const float*)d_in[11], (const float*)d_in[13]};
    const float* cW1  = (const float*)d_in[14];
    const float* cb1  = (const float*)d_in[15];
    const float* cg1  = (const float*)d_in[16];
    const float* cbt1 = (const float*)d_in[17];
    const float* cW2  = (const float*)d_in[18];
    const float* cb2  = (const float*)d_in[19];
    float* out = (float*)d_out;

    // workspace layout (4-byte units)
    float* ws      = (float*)d_ws;
    float* E       = ws;                           // NN*512  = 12,800,000
    float* Pparts  = E + (size_t)NN * 512;         // 4*NN*64 = 6,400,000
    float* dnorm_d = Pparts + (size_t)4 * NN * 64; // NE*8    = 3,200,000
    float* bufX    = dnorm_d + (size_t)NE * 8;     // NN*64
    float* bufY    = bufX + (size_t)NN * 64;       // NN*64
    float* sums    = bufY + (size_t)NN * 64;       // 64
    float* sumsq   = sums + 64;                    // 64
    float* pooled  = sumsq + 64;                   // 1024 (block reserved: 2048)
    int*   cnt     = (int*)(sums + 2048);          // NN
    int*   cur     = cnt + NN;                     // NN
    int*   dstoff  = cur + NN;                     // NN+1 (pad +8)
    int*   bsum    = dstoff + NN + 8;              // 128
    int*   boff    = bsum + 128;                   // 128
    int*   src_d   = boff + 128;                   // NE

    hipMemsetAsync(d_out, 0, (size_t)NG * NC * sizeof(float), stream);
    hipMemsetAsync(cnt, 0, NN * sizeof(int), stream);

    hist_k<<<(NE + 255) / 256, 256, 0, stream>>>(dst, cnt);
    scan_part_k<<<SCAN_NB, 256, 0, stream>>>(cnt, bsum);
    scan_mid_k<<<1, 128, 0, stream>>>(bsum, boff, dstoff);
    scan_final_k<<<SCAN_NB, 256, 0, stream>>>(cnt, boff, dstoff, cur);
    scatter_k<<<(NE + 255) / 256, 256, 0, stream>>>(src, dst, cemb, cur, src_d, dnorm_d);

    const float* h_old = feature;
    float* bufs[2] = {bufX, bufY};
    for (int l = 0; l < 3; l++) {
        float* agg = bufs[l & 1];
        hipMemsetAsync(sums, 0, 2048 * sizeof(float), stream);

        edge_E_k<<<NWE / 4, 256, 0, stream>>>(src_d, dstoff, dnorm_d, h_old, E);
        finish_gemm_part_k<<<dim3((NN + 63) / 64, 4), 256, 0, stream>>>(E, W[l], Pparts);
        combine_stats_k<<<512, 256, 0, stream>>>(Pparts, agg, sums, sumsq);
        bn_apply_k<<<256, 256, 0, stream>>>(agg, h_old, sums, sumsq, gam[l], bet[l],
                                            gids, agg, pooled, l > 0);
        classifier_k<<<1, 512, 0, stream>>>(pooled, cW1, cb1, cg1, cbt1, cW2, cb2, out);
        h_old = agg;
    }
}